// Round 1
// baseline (860.060 us; speedup 1.0000x reference)
//
#include <hip/hip_runtime.h>
#include <math.h>

#define N_NODES 50000
#define E_EDGES 800000
#define ETOT    (E_EDGES + N_NODES)

// ---------------------------------------------------------------------------
// GEMM + alpha epilogue: H = X @ W  [N x DOUT], asrc = H@a_s, adst = H@a_d
// One block = ROWS rows, DOUT threads per row (row-group is wave-aligned).
// W staged in LDS (<=32KB), X rows staged in LDS.
// ---------------------------------------------------------------------------
template<int DIN, int DOUT, int ROWS>
__global__ __launch_bounds__(ROWS * DOUT)
void gemm_alpha_kernel(const float* __restrict__ X, const float* __restrict__ W,
                       const float* __restrict__ a_s, const float* __restrict__ a_d,
                       float* __restrict__ H, float* __restrict__ asrc,
                       float* __restrict__ adst)
{
    __shared__ float Wl[DIN * DOUT];
    __shared__ float Al[ROWS][DIN];
    const int tid = threadIdx.x;
    const int nthreads = ROWS * DOUT;

    for (int i = tid; i < DIN * DOUT; i += nthreads) Wl[i] = W[i];
    const int row0 = blockIdx.x * ROWS;
    for (int i = tid; i < ROWS * DIN; i += nthreads) {
        int r = i / DIN, c = i % DIN;
        int gr = row0 + r;
        Al[r][c] = (gr < N_NODES) ? X[gr * DIN + c] : 0.f;
    }
    __syncthreads();

    const int r = tid / DOUT;
    const int f = tid % DOUT;
    const int grow = row0 + r;

    float sum = 0.f;
#pragma unroll 8
    for (int k = 0; k < DIN; ++k) sum += Al[r][k] * Wl[k * DOUT + f];

    // alpha partial products, reduce across the DOUT-lane row group
    float ps = sum * a_s[f];
    float pd = sum * a_d[f];
#pragma unroll
    for (int off = DOUT / 2; off >= 1; off >>= 1) {
        ps += __shfl_xor(ps, off, 64);
        pd += __shfl_xor(pd, off, 64);
    }

    if (grow < N_NODES) {
        H[grow * DOUT + f] = sum;
        if (f == 0) { asrc[grow] = ps; adst[grow] = pd; }
    }
}

// ---------------------------------------------------------------------------
// init: m = -inf, s = 0, acc = 0
// ---------------------------------------------------------------------------
template<int DOUT>
__global__ __launch_bounds__(256)
void init_kernel(float* __restrict__ m, float* __restrict__ s,
                 float* __restrict__ acc)
{
    int idx = blockIdx.x * blockDim.x + threadIdx.x;
    if (idx < N_NODES) { m[idx] = -INFINITY; s[idx] = 0.f; }
    if (idx < N_NODES * DOUT) acc[idx] = 0.f;
}

// ---------------------------------------------------------------------------
// edge pass A: e = leaky_relu(asrc[src]+adst[dst]); m[dst] = max(...)
// float atomic max via signed-int max / unsigned-int min trick
// ---------------------------------------------------------------------------
__global__ __launch_bounds__(256)
void edge_max_kernel(const int* __restrict__ ei, const float* __restrict__ asrc,
                     const float* __restrict__ adst, float* __restrict__ e,
                     float* __restrict__ m)
{
    int eid = blockIdx.x * blockDim.x + threadIdx.x;
    if (eid >= ETOT) return;
    int src, dst;
    if (eid < E_EDGES) { src = ei[eid]; dst = ei[E_EDGES + eid]; }
    else               { src = dst = eid - E_EDGES; }
    float v = asrc[src] + adst[dst];
    v = (v > 0.f) ? v : 0.2f * v;
    e[eid] = v;
    if (v >= 0.f) atomicMax((int*)(m + dst), __float_as_int(v));
    else          atomicMin((unsigned int*)(m + dst), __float_as_uint(v));
}

// ---------------------------------------------------------------------------
// edge pass B+C: ex = exp(e - m[dst]); s[dst] += ex; acc[dst,:] += ex*H[src,:]
// DOUT threads per edge, wave-aligned -> coalesced gather + coalesced atomics
// ---------------------------------------------------------------------------
template<int DOUT>
__global__ __launch_bounds__(256)
void edge_acc_kernel(const int* __restrict__ ei, const float* __restrict__ e,
                     const float* __restrict__ m, const float* __restrict__ H,
                     float* __restrict__ s, float* __restrict__ acc)
{
    const int epb = 256 / DOUT;
    int eid = blockIdx.x * epb + threadIdx.x / DOUT;
    int f   = threadIdx.x % DOUT;
    if (eid >= ETOT) return;
    int src, dst;
    if (eid < E_EDGES) { src = ei[eid]; dst = ei[E_EDGES + eid]; }
    else               { src = dst = eid - E_EDGES; }
    float ex = __expf(e[eid] - m[dst]);
    if (f == 0) atomicAdd(s + dst, ex);
    atomicAdd(acc + dst * DOUT + f, ex * H[src * DOUT + f]);
}

// ---------------------------------------------------------------------------
// finalize: out = act(acc/s + b);  ACT: 0=relu, 1=tanh
// ---------------------------------------------------------------------------
template<int DOUT, int ACT>
__global__ __launch_bounds__(256)
void finalize_kernel(const float* __restrict__ acc, const float* __restrict__ s,
                     const float* __restrict__ b, float* __restrict__ out)
{
    int idx = blockIdx.x * blockDim.x + threadIdx.x;
    if (idx >= N_NODES * DOUT) return;
    int n = idx / DOUT, f = idx % DOUT;
    float v = acc[idx] / s[n] + b[f];
    out[idx] = (ACT == 0) ? fmaxf(v, 0.f) : tanhf(v);
}

// ---------------------------------------------------------------------------

template<int DIN, int DOUT, int ACT>
static void run_layer(const float* X, const float* W, const float* a_s,
                      const float* a_d, const float* b, const int* ei,
                      float* H, float* asrc, float* adst, float* mbuf,
                      float* sbuf, float* ebuf, float* acc, float* out,
                      hipStream_t stream)
{
    constexpr int ROWS = 256 / DOUT;
    const int gemm_grid = (N_NODES + ROWS - 1) / ROWS;
    gemm_alpha_kernel<DIN, DOUT, ROWS><<<gemm_grid, ROWS * DOUT, 0, stream>>>(
        X, W, a_s, a_d, H, asrc, adst);

    const int init_grid = (N_NODES * DOUT + 255) / 256;
    init_kernel<DOUT><<<init_grid, 256, 0, stream>>>(mbuf, sbuf, acc);

    const int emax_grid = (ETOT + 255) / 256;
    edge_max_kernel<<<emax_grid, 256, 0, stream>>>(ei, asrc, adst, ebuf, mbuf);

    constexpr int epb = 256 / DOUT;
    const int eacc_grid = (ETOT + epb - 1) / epb;
    edge_acc_kernel<DOUT><<<eacc_grid, 256, 0, stream>>>(ei, ebuf, mbuf, H,
                                                         sbuf, acc);

    const int fin_grid = (N_NODES * DOUT + 255) / 256;
    finalize_kernel<DOUT, ACT><<<fin_grid, 256, 0, stream>>>(acc, sbuf, b, out);
}

extern "C" void kernel_launch(void* const* d_in, const int* in_sizes, int n_in,
                              void* d_out, int out_size, void* d_ws, size_t ws_size,
                              hipStream_t stream)
{
    const float* x  = (const float*)d_in[0];
    const int*   ei = (const int*)d_in[1];
    const float* W0 = (const float*)d_in[2];
    const float* as0= (const float*)d_in[3];
    const float* ad0= (const float*)d_in[4];
    const float* b0 = (const float*)d_in[5];
    const float* W1 = (const float*)d_in[6];
    const float* as1= (const float*)d_in[7];
    const float* ad1= (const float*)d_in[8];
    const float* b1 = (const float*)d_in[9];
    const float* W2 = (const float*)d_in[10];
    const float* as2= (const float*)d_in[11];
    const float* ad2= (const float*)d_in[12];
    const float* b2 = (const float*)d_in[13];
    float* out = (float*)d_out;

    float* ws      = (float*)d_ws;
    float* buf_h   = ws;                       // N*64
    float* buf_acc = buf_h   + N_NODES * 64;   // N*64
    float* buf_act = buf_acc + N_NODES * 64;   // N*64
    float* asrc    = buf_act + N_NODES * 64;   // N
    float* adst    = asrc    + N_NODES;        // N
    float* mbuf    = adst    + N_NODES;        // N
    float* sbuf    = mbuf    + N_NODES;        // N
    float* ebuf    = sbuf    + N_NODES;        // ETOT

    // layer 0: 128 -> 64, relu
    run_layer<128, 64, 0>(x, W0, as0, ad0, b0, ei, buf_h, asrc, adst, mbuf,
                          sbuf, ebuf, buf_acc, buf_act, stream);
    // layer 1: 64 -> 64, relu
    run_layer<64, 64, 0>(buf_act, W1, as1, ad1, b1, ei, buf_h, asrc, adst,
                         mbuf, sbuf, ebuf, buf_acc, buf_act, stream);
    // layer 2: 64 -> 32, tanh
    run_layer<64, 32, 1>(buf_act, W2, as2, ad2, b2, ei, buf_h, asrc, adst,
                         mbuf, sbuf, ebuf, buf_acc, out, stream);
}

// Round 2
// 489.020 us; speedup vs baseline: 1.7587x; 1.7587x over previous
//
#include <hip/hip_runtime.h>
#include <math.h>

#define N_NODES 50000
#define E_EDGES 800000
#define ETOT    (E_EDGES + N_NODES)

// ---------------------------------------------------------------------------
// GEMM + alpha epilogue: H = X @ W  [N x DOUT], asrc = H@a_s, adst = H@a_d
// ---------------------------------------------------------------------------
template<int DIN, int DOUT, int ROWS>
__global__ __launch_bounds__(ROWS * DOUT)
void gemm_alpha_kernel(const float* __restrict__ X, const float* __restrict__ W,
                       const float* __restrict__ a_s, const float* __restrict__ a_d,
                       float* __restrict__ H, float* __restrict__ asrc,
                       float* __restrict__ adst)
{
    __shared__ float Wl[DIN * DOUT];
    __shared__ float Al[ROWS][DIN];
    const int tid = threadIdx.x;
    const int nthreads = ROWS * DOUT;

    for (int i = tid; i < DIN * DOUT; i += nthreads) Wl[i] = W[i];
    const int row0 = blockIdx.x * ROWS;
    for (int i = tid; i < ROWS * DIN; i += nthreads) {
        int r = i / DIN, c = i % DIN;
        int gr = row0 + r;
        Al[r][c] = (gr < N_NODES) ? X[gr * DIN + c] : 0.f;
    }
    __syncthreads();

    const int r = tid / DOUT;
    const int f = tid % DOUT;
    const int grow = row0 + r;

    float sum = 0.f;
#pragma unroll 8
    for (int k = 0; k < DIN; ++k) sum += Al[r][k] * Wl[k * DOUT + f];

    float ps = sum * a_s[f];
    float pd = sum * a_d[f];
#pragma unroll
    for (int off = DOUT / 2; off >= 1; off >>= 1) {
        ps += __shfl_xor(ps, off, 64);
        pd += __shfl_xor(pd, off, 64);
    }

    if (grow < N_NODES) {
        H[grow * DOUT + f] = sum;
        if (f == 0) { asrc[grow] = ps; adst[grow] = pd; }
    }
}

// ---------------------------------------------------------------------------
// CSR build (once, reused by all 3 layers)
// ---------------------------------------------------------------------------
__global__ __launch_bounds__(256)
void zero_deg_kernel(int* __restrict__ deg)
{
    int i = blockIdx.x * blockDim.x + threadIdx.x;
    if (i < N_NODES) deg[i] = 0;
}

__global__ __launch_bounds__(256)
void deg_kernel(const int* __restrict__ ei, int* __restrict__ deg)
{
    int eid = blockIdx.x * blockDim.x + threadIdx.x;
    if (eid >= ETOT) return;
    int dst = (eid < E_EDGES) ? ei[E_EDGES + eid] : (eid - E_EDGES);
    atomicAdd(deg + dst, 1);
}

// single-block exclusive scan of deg[N] -> offs[N+1], copy to woff[N]
__global__ __launch_bounds__(1024)
void scan_kernel(const int* __restrict__ deg, int* __restrict__ offs,
                 int* __restrict__ woff)
{
    __shared__ int part[1024];
    const int T = 1024;
    const int t = threadIdx.x;
    const int per = (N_NODES + T - 1) / T;
    const int base = t * per;

    int sum = 0;
    for (int i = 0; i < per; ++i) {
        int idx = base + i;
        if (idx < N_NODES) sum += deg[idx];
    }
    part[t] = sum;
    __syncthreads();
    for (int off = 1; off < T; off <<= 1) {
        int v = (t >= off) ? part[t - off] : 0;
        __syncthreads();
        part[t] += v;
        __syncthreads();
    }
    int run = (t > 0) ? part[t - 1] : 0;
    for (int i = 0; i < per; ++i) {
        int idx = base + i;
        if (idx < N_NODES) {
            offs[idx] = run;
            woff[idx] = run;
            run += deg[idx];
        }
    }
    if (t == 0) offs[N_NODES] = part[T - 1];
}

__global__ __launch_bounds__(256)
void scatter_kernel(const int* __restrict__ ei, int* __restrict__ woff,
                    int* __restrict__ csr_src)
{
    int eid = blockIdx.x * blockDim.x + threadIdx.x;
    if (eid >= ETOT) return;
    int src, dst;
    if (eid < E_EDGES) { src = ei[eid]; dst = ei[E_EDGES + eid]; }
    else               { src = dst = eid - E_EDGES; }
    int pos = atomicAdd(woff + dst, 1);
    csr_src[pos] = src;
}

// ---------------------------------------------------------------------------
// Per-dst-node flash-style softmax aggregation, fused finalize.
// G = DOUT lanes per node (64 or 32). Chunked over edges, online rescale.
// ---------------------------------------------------------------------------
template<int DOUT, int ACT>
__global__ __launch_bounds__(256)
void node_agg_kernel(const int* __restrict__ offs, const int* __restrict__ csr_src,
                     const float* __restrict__ asrc, const float* __restrict__ adst,
                     const float* __restrict__ H, const float* __restrict__ b,
                     float* __restrict__ out)
{
    constexpr int G = DOUT;          // lanes per node group
    const int gpb = 256 / G;
    const int node = blockIdx.x * gpb + threadIdx.x / G;
    const int lane = threadIdx.x % G;
    if (node >= N_NODES) return;

    const int beg = offs[node];
    const int end = offs[node + 1];
    const float adn = adst[node];

    float m = -INFINITY, s = 0.f, acc = 0.f;

    for (int cbeg = beg; cbeg < end; cbeg += G) {
        const int cnt = min(G, end - cbeg);
        int src = 0;
        float e = -INFINITY;
        if (lane < cnt) {
            src = csr_src[cbeg + lane];
            float v = asrc[src] + adn;
            e = (v > 0.f) ? v : 0.2f * v;
        }
        // group max
        float cm = e;
#pragma unroll
        for (int off = G / 2; off >= 1; off >>= 1)
            cm = fmaxf(cm, __shfl_xor(cm, off, G));
        const float nm = fmaxf(m, cm);
        const float scale = __expf(m - nm);   // first chunk: exp(-inf)=0, s=acc=0
        s *= scale;
        acc *= scale;
        float p = (lane < cnt) ? __expf(e - nm) : 0.f;
        float ssum = p;
#pragma unroll
        for (int off = G / 2; off >= 1; off >>= 1)
            ssum += __shfl_xor(ssum, off, G);
        s += ssum;
        m = nm;
        for (int j = 0; j < cnt; ++j) {
            const float pj = __shfl(p, j, G);
            const int sj = __shfl(src, j, G);
            acc += pj * H[sj * DOUT + lane];
        }
    }

    float v = acc / s + b[lane];
    out[node * DOUT + lane] = (ACT == 0) ? fmaxf(v, 0.f) : tanhf(v);
}

// ---------------------------------------------------------------------------

template<int DIN, int DOUT, int ACT>
static void run_layer(const float* X, const float* W, const float* a_s,
                      const float* a_d, const float* b,
                      const int* offs, const int* csr_src,
                      float* H, float* asrc, float* adst, float* out,
                      hipStream_t stream)
{
    constexpr int ROWS = 256 / DOUT;
    const int gemm_grid = (N_NODES + ROWS - 1) / ROWS;
    gemm_alpha_kernel<DIN, DOUT, ROWS><<<gemm_grid, ROWS * DOUT, 0, stream>>>(
        X, W, a_s, a_d, H, asrc, adst);

    constexpr int gpb = 256 / DOUT;
    const int agg_grid = (N_NODES + gpb - 1) / gpb;
    node_agg_kernel<DOUT, ACT><<<agg_grid, 256, 0, stream>>>(
        offs, csr_src, asrc, adst, H, b, out);
}

extern "C" void kernel_launch(void* const* d_in, const int* in_sizes, int n_in,
                              void* d_out, int out_size, void* d_ws, size_t ws_size,
                              hipStream_t stream)
{
    const float* x  = (const float*)d_in[0];
    const int*   ei = (const int*)d_in[1];
    const float* W0 = (const float*)d_in[2];
    const float* as0= (const float*)d_in[3];
    const float* ad0= (const float*)d_in[4];
    const float* b0 = (const float*)d_in[5];
    const float* W1 = (const float*)d_in[6];
    const float* as1= (const float*)d_in[7];
    const float* ad1= (const float*)d_in[8];
    const float* b1 = (const float*)d_in[9];
    const float* W2 = (const float*)d_in[10];
    const float* as2= (const float*)d_in[11];
    const float* ad2= (const float*)d_in[12];
    const float* b2 = (const float*)d_in[13];
    float* out = (float*)d_out;

    // workspace layout
    char* wsb = (char*)d_ws;
    int*  deg     = (int*)wsb;                      wsb += sizeof(int) * N_NODES;
    int*  offs    = (int*)wsb;                      wsb += sizeof(int) * (N_NODES + 1);
    int*  woff    = (int*)wsb;                      wsb += sizeof(int) * N_NODES;
    int*  csr_src = (int*)wsb;                      wsb += sizeof(int) * ETOT;
    float* buf_h  = (float*)wsb;                    wsb += sizeof(float) * N_NODES * 64;
    float* buf_act= (float*)wsb;                    wsb += sizeof(float) * N_NODES * 64;
    float* asrc   = (float*)wsb;                    wsb += sizeof(float) * N_NODES;
    float* adst   = (float*)wsb;                    wsb += sizeof(float) * N_NODES;

    // ---- CSR build (edge structure shared by all layers) ----
    const int ngrid = (N_NODES + 255) / 256;
    const int egrid = (ETOT + 255) / 256;
    zero_deg_kernel<<<ngrid, 256, 0, stream>>>(deg);
    deg_kernel<<<egrid, 256, 0, stream>>>(ei, deg);
    scan_kernel<<<1, 1024, 0, stream>>>(deg, offs, woff);
    scatter_kernel<<<egrid, 256, 0, stream>>>(ei, woff, csr_src);

    // ---- layers ----
    run_layer<128, 64, 0>(x, W0, as0, ad0, b0, offs, csr_src,
                          buf_h, asrc, adst, buf_act, stream);
    run_layer<64, 64, 0>(buf_act, W1, as1, ad1, b1, offs, csr_src,
                         buf_h, asrc, adst, buf_act, stream);
    run_layer<64, 32, 1>(buf_act, W2, as2, ad2, b2, offs, csr_src,
                         buf_h, asrc, adst, out, stream);
}

// Round 3
// 373.535 us; speedup vs baseline: 2.3025x; 1.3092x over previous
//
#include <hip/hip_runtime.h>
#include <math.h>

#define N_NODES 50000
#define E_EDGES 800000
#define ETOT    (E_EDGES + N_NODES)
#define SCAN_CHUNK 1024
#define SCAN_NB ((N_NODES + SCAN_CHUNK - 1) / SCAN_CHUNK)   // 49

// ---------------------------------------------------------------------------
// GEMM + alpha epilogue: H = X @ W  [N x DOUT], asrc = H@a_s, adst = H@a_d
// ---------------------------------------------------------------------------
template<int DIN, int DOUT, int ROWS>
__global__ __launch_bounds__(ROWS * DOUT)
void gemm_alpha_kernel(const float* __restrict__ X, const float* __restrict__ W,
                       const float* __restrict__ a_s, const float* __restrict__ a_d,
                       float* __restrict__ H, float* __restrict__ asrc,
                       float* __restrict__ adst)
{
    __shared__ float Wl[DIN * DOUT];
    __shared__ float Al[ROWS][DIN];
    const int tid = threadIdx.x;
    const int nthreads = ROWS * DOUT;

    for (int i = tid; i < DIN * DOUT; i += nthreads) Wl[i] = W[i];
    const int row0 = blockIdx.x * ROWS;
    for (int i = tid; i < ROWS * DIN; i += nthreads) {
        int r = i / DIN, c = i % DIN;
        int gr = row0 + r;
        Al[r][c] = (gr < N_NODES) ? X[gr * DIN + c] : 0.f;
    }
    __syncthreads();

    const int r = tid / DOUT;
    const int f = tid % DOUT;
    const int grow = row0 + r;

    float sum = 0.f;
#pragma unroll 8
    for (int k = 0; k < DIN; ++k) sum += Al[r][k] * Wl[k * DOUT + f];

    float ps = sum * a_s[f];
    float pd = sum * a_d[f];
#pragma unroll
    for (int off = DOUT / 2; off >= 1; off >>= 1) {
        ps += __shfl_xor(ps, off, 64);
        pd += __shfl_xor(pd, off, 64);
    }

    if (grow < N_NODES) {
        H[grow * DOUT + f] = sum;
        if (f == 0) { asrc[grow] = ps; adst[grow] = pd; }
    }
}

// ---------------------------------------------------------------------------
// CSR build (once, reused by all 3 layers)
// ---------------------------------------------------------------------------
__global__ __launch_bounds__(256)
void zero_deg_kernel(int* __restrict__ deg)
{
    int i = blockIdx.x * blockDim.x + threadIdx.x;
    if (i < N_NODES) deg[i] = 0;
}

__global__ __launch_bounds__(256)
void deg_kernel(const int* __restrict__ ei, int* __restrict__ deg)
{
    int eid = blockIdx.x * blockDim.x + threadIdx.x;
    if (eid >= ETOT) return;
    int dst = (eid < E_EDGES) ? ei[E_EDGES + eid] : (eid - E_EDGES);
    atomicAdd(deg + dst, 1);
}

// --- hierarchical scan: A) per-chunk sums ---
__global__ __launch_bounds__(256)
void scan_part_kernel(const int* __restrict__ deg, int* __restrict__ bsum)
{
    __shared__ int lds[256];
    const int base = blockIdx.x * SCAN_CHUNK;
    int sum = 0;
    for (int i = threadIdx.x; i < SCAN_CHUNK; i += 256) {
        int idx = base + i;
        sum += (idx < N_NODES) ? deg[idx] : 0;
    }
    lds[threadIdx.x] = sum;
    __syncthreads();
    for (int off = 128; off >= 1; off >>= 1) {
        if (threadIdx.x < off) lds[threadIdx.x] += lds[threadIdx.x + off];
        __syncthreads();
    }
    if (threadIdx.x == 0) bsum[blockIdx.x] = lds[0];
}

// --- B) exclusive scan of SCAN_NB block sums in one wave ---
__global__ __launch_bounds__(64)
void scan_top_kernel(int* __restrict__ bsum)
{
    const int t = threadIdx.x;
    int v = (t < SCAN_NB) ? bsum[t] : 0;
    for (int off = 1; off < 64; off <<= 1) {
        int u = __shfl_up(v, off, 64);
        if (t >= off) v += u;
    }
    int ex = __shfl_up(v, 1, 64);
    if (t == 0) ex = 0;
    if (t < SCAN_NB) bsum[t] = ex;
}

// --- C) local scan + block offset -> offs, woff ---
__global__ __launch_bounds__(256)
void scan_out_kernel(const int* __restrict__ deg, const int* __restrict__ bsum,
                     int* __restrict__ offs, int* __restrict__ woff)
{
    __shared__ int lds[256];
    const int t = threadIdx.x;
    const int idx0 = blockIdx.x * SCAN_CHUNK + t * 4;
    int v[4];
    int tsum = 0;
#pragma unroll
    for (int i = 0; i < 4; ++i) {
        int idx = idx0 + i;
        v[i] = (idx < N_NODES) ? deg[idx] : 0;
        tsum += v[i];
    }
    lds[t] = tsum;
    __syncthreads();
    for (int off = 1; off < 256; off <<= 1) {
        int u = (t >= off) ? lds[t - off] : 0;
        __syncthreads();
        lds[t] += u;
        __syncthreads();
    }
    int run = bsum[blockIdx.x] + ((t > 0) ? lds[t - 1] : 0);
#pragma unroll
    for (int i = 0; i < 4; ++i) {
        int idx = idx0 + i;
        if (idx < N_NODES) { offs[idx] = run; woff[idx] = run; run += v[i]; }
    }
    if (blockIdx.x == 0 && t == 0) offs[N_NODES] = ETOT;
}

__global__ __launch_bounds__(256)
void scatter_kernel(const int* __restrict__ ei, int* __restrict__ woff,
                    int* __restrict__ csr_src)
{
    int eid = blockIdx.x * blockDim.x + threadIdx.x;
    if (eid >= ETOT) return;
    int src, dst;
    if (eid < E_EDGES) { src = ei[eid]; dst = ei[E_EDGES + eid]; }
    else               { src = dst = eid - E_EDGES; }
    int pos = atomicAdd(woff + dst, 1);
    csr_src[pos] = src;
}

// ---------------------------------------------------------------------------
// Per-dst-node flash-style softmax aggregation, fused finalize.
// ---------------------------------------------------------------------------
template<int DOUT, int ACT>
__global__ __launch_bounds__(256)
void node_agg_kernel(const int* __restrict__ offs, const int* __restrict__ csr_src,
                     const float* __restrict__ asrc, const float* __restrict__ adst,
                     const float* __restrict__ H, const float* __restrict__ b,
                     float* __restrict__ out)
{
    constexpr int G = DOUT;
    const int gpb = 256 / G;
    const int node = blockIdx.x * gpb + threadIdx.x / G;
    const int lane = threadIdx.x % G;
    if (node >= N_NODES) return;

    const int beg = offs[node];
    const int end = offs[node + 1];
    const float adn = adst[node];

    float m = -INFINITY, s = 0.f, acc = 0.f;

    for (int cbeg = beg; cbeg < end; cbeg += G) {
        const int cnt = min(G, end - cbeg);
        int src = 0;
        float e = -INFINITY;
        if (lane < cnt) {
            src = csr_src[cbeg + lane];
            float v = asrc[src] + adn;
            e = (v > 0.f) ? v : 0.2f * v;
        }
        float cm = e;
#pragma unroll
        for (int off = G / 2; off >= 1; off >>= 1)
            cm = fmaxf(cm, __shfl_xor(cm, off, G));
        const float nm = fmaxf(m, cm);
        const float scale = __expf(m - nm);
        s *= scale;
        acc *= scale;
        float p = (lane < cnt) ? __expf(e - nm) : 0.f;
        float ssum = p;
#pragma unroll
        for (int off = G / 2; off >= 1; off >>= 1)
            ssum += __shfl_xor(ssum, off, G);
        s += ssum;
        m = nm;
        for (int j = 0; j < cnt; ++j) {
            const float pj = __shfl(p, j, G);
            const int sj = __shfl(src, j, G);
            acc += pj * H[sj * DOUT + lane];
        }
    }

    float v = acc / s + b[lane];
    out[node * DOUT + lane] = (ACT == 0) ? fmaxf(v, 0.f) : tanhf(v);
}

// ---------------------------------------------------------------------------

template<int DIN, int DOUT, int ACT>
static void run_layer(const float* X, const float* W, const float* a_s,
                      const float* a_d, const float* b,
                      const int* offs, const int* csr_src,
                      float* H, float* asrc, float* adst, float* out,
                      hipStream_t stream)
{
    constexpr int ROWS = 256 / DOUT;
    const int gemm_grid = (N_NODES + ROWS - 1) / ROWS;
    gemm_alpha_kernel<DIN, DOUT, ROWS><<<gemm_grid, ROWS * DOUT, 0, stream>>>(
        X, W, a_s, a_d, H, asrc, adst);

    constexpr int gpb = 256 / DOUT;
    const int agg_grid = (N_NODES + gpb - 1) / gpb;
    node_agg_kernel<DOUT, ACT><<<agg_grid, 256, 0, stream>>>(
        offs, csr_src, asrc, adst, H, b, out);
}

extern "C" void kernel_launch(void* const* d_in, const int* in_sizes, int n_in,
                              void* d_out, int out_size, void* d_ws, size_t ws_size,
                              hipStream_t stream)
{
    const float* x  = (const float*)d_in[0];
    const int*   ei = (const int*)d_in[1];
    const float* W0 = (const float*)d_in[2];
    const float* as0= (const float*)d_in[3];
    const float* ad0= (const float*)d_in[4];
    const float* b0 = (const float*)d_in[5];
    const float* W1 = (const float*)d_in[6];
    const float* as1= (const float*)d_in[7];
    const float* ad1= (const float*)d_in[8];
    const float* b1 = (const float*)d_in[9];
    const float* W2 = (const float*)d_in[10];
    const float* as2= (const float*)d_in[11];
    const float* ad2= (const float*)d_in[12];
    const float* b2 = (const float*)d_in[13];
    float* out = (float*)d_out;

    // workspace layout
    char* wsb = (char*)d_ws;
    int*  deg     = (int*)wsb;                      wsb += sizeof(int) * N_NODES;
    int*  offs    = (int*)wsb;                      wsb += sizeof(int) * (N_NODES + 1);
    int*  woff    = (int*)wsb;                      wsb += sizeof(int) * N_NODES;
    int*  bsum    = (int*)wsb;                      wsb += sizeof(int) * SCAN_NB;
    int*  csr_src = (int*)wsb;                      wsb += sizeof(int) * ETOT;
    float* buf_h  = (float*)wsb;                    wsb += sizeof(float) * N_NODES * 64;
    float* buf_act= (float*)wsb;                    wsb += sizeof(float) * N_NODES * 64;
    float* asrc   = (float*)wsb;                    wsb += sizeof(float) * N_NODES;
    float* adst   = (float*)wsb;                    wsb += sizeof(float) * N_NODES;

    // ---- CSR build ----
    const int ngrid = (N_NODES + 255) / 256;
    const int egrid = (ETOT + 255) / 256;
    zero_deg_kernel<<<ngrid, 256, 0, stream>>>(deg);
    deg_kernel<<<egrid, 256, 0, stream>>>(ei, deg);
    scan_part_kernel<<<SCAN_NB, 256, 0, stream>>>(deg, bsum);
    scan_top_kernel<<<1, 64, 0, stream>>>(bsum);
    scan_out_kernel<<<SCAN_NB, 256, 0, stream>>>(deg, bsum, offs, woff);
    scatter_kernel<<<egrid, 256, 0, stream>>>(ei, woff, csr_src);

    // ---- layers ----
    run_layer<128, 64, 0>(x, W0, as0, ad0, b0, offs, csr_src,
                          buf_h, asrc, adst, buf_act, stream);
    run_layer<64, 64, 0>(buf_act, W1, as1, ad1, b1, offs, csr_src,
                         buf_h, asrc, adst, buf_act, stream);
    run_layer<64, 32, 1>(buf_act, W2, as2, ad2, b2, offs, csr_src,
                         buf_h, asrc, adst, out, stream);
}

// Round 4
// 272.971 us; speedup vs baseline: 3.1507x; 1.3684x over previous
//
#include <hip/hip_runtime.h>
#include <math.h>

#define N_NODES 50000
#define E_EDGES 800000
#define ETOT    (E_EDGES + N_NODES)
#define SCAN_CHUNK 1024
#define SCAN_NB ((N_NODES + SCAN_CHUNK - 1) / SCAN_CHUNK)   // 49

// ---------------------------------------------------------------------------
// Register-tiled GEMM + alpha epilogue.
// 256 threads; micro-tile 4x4 per thread. COLG = DOUT/4 col-groups,
// ROWG = 256/COLG row-groups, BM = ROWG*4 rows per block.
// X tile in LDS with XOR-swizzled float4 index (bank-conflict-free reads,
// no padding so layer0 fits exactly in 64KB). W tile plain.
// ---------------------------------------------------------------------------
template<int DIN, int DOUT>
__global__ __launch_bounds__(256)
void gemm_alpha_kernel(const float* __restrict__ X, const float* __restrict__ W,
                       const float* __restrict__ a_s, const float* __restrict__ a_d,
                       float* __restrict__ H, float* __restrict__ asrc,
                       float* __restrict__ adst)
{
    constexpr int COLG = DOUT / 4;     // 16 (dout=64) or 8 (dout=32)
    constexpr int ROWG = 256 / COLG;   // 16 or 32
    constexpr int BM   = ROWG * 4;     // 64 or 128
    constexpr int K4   = DIN / 4;      // float4s per row

    __shared__ float Xl[BM * DIN];
    __shared__ float Wl[DIN * DOUT];

    const int tid = threadIdx.x;
    const int row0b = blockIdx.x * BM;

    // stage W (flat float4 copy)
    constexpr int WV = DIN * DOUT / 4;
    for (int i = tid; i < WV; i += 256)
        ((float4*)Wl)[i] = ((const float4*)W)[i];

    // stage X tile, swizzled: float4 j within row r stored at j ^ ((r>>2)&7)
    constexpr int XV = BM * K4;
    for (int i = tid; i < XV; i += 256) {
        int r  = i / K4;
        int j  = i % K4;
        int gr = row0b + r;
        float4 v = make_float4(0.f, 0.f, 0.f, 0.f);
        if (gr < N_NODES) v = ((const float4*)X)[gr * K4 + j];
        *(float4*)&Xl[r * DIN + ((j ^ ((r >> 2) & 7)) << 2)] = v;
    }
    __syncthreads();

    const int tx = tid % COLG;
    const int ty = tid / COLG;
    const int r0 = ty * 4;
    const int c0 = tx * 4;
    const int swz = ty & 7;

    float acc[4][4] = {};
    for (int kk = 0; kk < DIN; kk += 4) {
        float a[4][4], w[4][4];
        const int jk = ((kk >> 2) ^ swz) << 2;
#pragma unroll
        for (int i = 0; i < 4; ++i)
            *(float4*)a[i] = *(const float4*)&Xl[(r0 + i) * DIN + jk];
#pragma unroll
        for (int j = 0; j < 4; ++j)
            *(float4*)w[j] = *(const float4*)&Wl[(kk + j) * DOUT + c0];
#pragma unroll
        for (int i = 0; i < 4; ++i)
#pragma unroll
            for (int j = 0; j < 4; ++j)
                acc[i][j] = fmaf(a[i][0], w[0][j],
                            fmaf(a[i][1], w[1][j],
                            fmaf(a[i][2], w[2][j],
                            fmaf(a[i][3], w[3][j], acc[i][j]))));
    }

    float as4[4], ad4[4];
    *(float4*)as4 = *(const float4*)&a_s[c0];
    *(float4*)ad4 = *(const float4*)&a_d[c0];

#pragma unroll
    for (int i = 0; i < 4; ++i) {
        const int gr = row0b + r0 + i;
        float ps = acc[i][0] * as4[0] + acc[i][1] * as4[1] +
                   acc[i][2] * as4[2] + acc[i][3] * as4[3];
        float pd = acc[i][0] * ad4[0] + acc[i][1] * ad4[1] +
                   acc[i][2] * ad4[2] + acc[i][3] * ad4[3];
#pragma unroll
        for (int off = COLG / 2; off >= 1; off >>= 1) {
            ps += __shfl_xor(ps, off, 64);
            pd += __shfl_xor(pd, off, 64);
        }
        if (gr < N_NODES) {
            *(float4*)&H[gr * DOUT + c0] = *(float4*)acc[i];
            if (tx == 0) { asrc[gr] = ps; adst[gr] = pd; }
        }
    }
}

// ---------------------------------------------------------------------------
// CSR build (once, reused by all 3 layers)
// ---------------------------------------------------------------------------
__global__ __launch_bounds__(256)
void zero_deg_kernel(int* __restrict__ deg)
{
    int i = blockIdx.x * blockDim.x + threadIdx.x;
    if (i < N_NODES) deg[i] = 0;
}

__global__ __launch_bounds__(256)
void deg_kernel(const int* __restrict__ ei, int* __restrict__ deg)
{
    int eid = blockIdx.x * blockDim.x + threadIdx.x;
    if (eid >= ETOT) return;
    int dst = (eid < E_EDGES) ? ei[E_EDGES + eid] : (eid - E_EDGES);
    atomicAdd(deg + dst, 1);
}

__global__ __launch_bounds__(256)
void scan_part_kernel(const int* __restrict__ deg, int* __restrict__ bsum)
{
    __shared__ int lds[256];
    const int base = blockIdx.x * SCAN_CHUNK;
    int sum = 0;
    for (int i = threadIdx.x; i < SCAN_CHUNK; i += 256) {
        int idx = base + i;
        sum += (idx < N_NODES) ? deg[idx] : 0;
    }
    lds[threadIdx.x] = sum;
    __syncthreads();
    for (int off = 128; off >= 1; off >>= 1) {
        if (threadIdx.x < off) lds[threadIdx.x] += lds[threadIdx.x + off];
        __syncthreads();
    }
    if (threadIdx.x == 0) bsum[blockIdx.x] = lds[0];
}

__global__ __launch_bounds__(64)
void scan_top_kernel(int* __restrict__ bsum)
{
    const int t = threadIdx.x;
    int v = (t < SCAN_NB) ? bsum[t] : 0;
    for (int off = 1; off < 64; off <<= 1) {
        int u = __shfl_up(v, off, 64);
        if (t >= off) v += u;
    }
    int ex = __shfl_up(v, 1, 64);
    if (t == 0) ex = 0;
    if (t < SCAN_NB) bsum[t] = ex;
}

__global__ __launch_bounds__(256)
void scan_out_kernel(const int* __restrict__ deg, const int* __restrict__ bsum,
                     int* __restrict__ offs, int* __restrict__ woff)
{
    __shared__ int lds[256];
    const int t = threadIdx.x;
    const int idx0 = blockIdx.x * SCAN_CHUNK + t * 4;
    int v[4];
    int tsum = 0;
#pragma unroll
    for (int i = 0; i < 4; ++i) {
        int idx = idx0 + i;
        v[i] = (idx < N_NODES) ? deg[idx] : 0;
        tsum += v[i];
    }
    lds[t] = tsum;
    __syncthreads();
    for (int off = 1; off < 256; off <<= 1) {
        int u = (t >= off) ? lds[t - off] : 0;
        __syncthreads();
        lds[t] += u;
        __syncthreads();
    }
    int run = bsum[blockIdx.x] + ((t > 0) ? lds[t - 1] : 0);
#pragma unroll
    for (int i = 0; i < 4; ++i) {
        int idx = idx0 + i;
        if (idx < N_NODES) { offs[idx] = run; woff[idx] = run; run += v[i]; }
    }
    if (blockIdx.x == 0 && t == 0) offs[N_NODES] = ETOT;
}

__global__ __launch_bounds__(256)
void scatter_kernel(const int* __restrict__ ei, int* __restrict__ woff,
                    int* __restrict__ csr_src)
{
    int eid = blockIdx.x * blockDim.x + threadIdx.x;
    if (eid >= ETOT) return;
    int src, dst;
    if (eid < E_EDGES) { src = ei[eid]; dst = ei[E_EDGES + eid]; }
    else               { src = dst = eid - E_EDGES; }
    int pos = atomicAdd(woff + dst, 1);
    csr_src[pos] = src;
}

// ---------------------------------------------------------------------------
// Per-dst-node flash-style softmax aggregation, fused finalize.
// Gather loop unrolled x4 -> 4 independent H-row loads in flight.
// ---------------------------------------------------------------------------
template<int DOUT, int ACT>
__global__ __launch_bounds__(256)
void node_agg_kernel(const int* __restrict__ offs, const int* __restrict__ csr_src,
                     const float* __restrict__ asrc, const float* __restrict__ adst,
                     const float* __restrict__ H, const float* __restrict__ b,
                     float* __restrict__ out)
{
    constexpr int G = DOUT;
    const int gpb = 256 / G;
    const int node = blockIdx.x * gpb + threadIdx.x / G;
    const int lane = threadIdx.x % G;
    if (node >= N_NODES) return;

    const int beg = offs[node];
    const int end = offs[node + 1];
    const float adn = adst[node];

    float m = -INFINITY, s = 0.f, acc = 0.f;

    for (int cbeg = beg; cbeg < end; cbeg += G) {
        const int cnt = min(G, end - cbeg);
        int src = 0;
        float e = -INFINITY;
        if (lane < cnt) {
            src = csr_src[cbeg + lane];
            float v = asrc[src] + adn;
            e = (v > 0.f) ? v : 0.2f * v;
        }
        float cm = e;
#pragma unroll
        for (int off = G / 2; off >= 1; off >>= 1)
            cm = fmaxf(cm, __shfl_xor(cm, off, G));
        const float nm = fmaxf(m, cm);
        const float scale = __expf(m - nm);
        s *= scale;
        acc *= scale;
        float p = (lane < cnt) ? __expf(e - nm) : 0.f;
        float ssum = p;
#pragma unroll
        for (int off = G / 2; off >= 1; off >>= 1)
            ssum += __shfl_xor(ssum, off, G);
        s += ssum;
        m = nm;

        int j = 0;
        for (; j + 3 < cnt; j += 4) {
            const float p0 = __shfl(p, j,     G);
            const float p1 = __shfl(p, j + 1, G);
            const float p2 = __shfl(p, j + 2, G);
            const float p3 = __shfl(p, j + 3, G);
            const int   s0 = __shfl(src, j,     G);
            const int   s1 = __shfl(src, j + 1, G);
            const int   s2 = __shfl(src, j + 2, G);
            const int   s3 = __shfl(src, j + 3, G);
            const float h0 = H[s0 * DOUT + lane];
            const float h1 = H[s1 * DOUT + lane];
            const float h2 = H[s2 * DOUT + lane];
            const float h3 = H[s3 * DOUT + lane];
            acc = fmaf(p0, h0, acc);
            acc = fmaf(p1, h1, acc);
            acc = fmaf(p2, h2, acc);
            acc = fmaf(p3, h3, acc);
        }
        for (; j < cnt; ++j) {
            const float pj = __shfl(p, j, G);
            const int   sj = __shfl(src, j, G);
            acc = fmaf(pj, H[sj * DOUT + lane], acc);
        }
    }

    float v = acc / s + b[lane];
    out[node * DOUT + lane] = (ACT == 0) ? fmaxf(v, 0.f) : tanhf(v);
}

// ---------------------------------------------------------------------------

template<int DIN, int DOUT, int ACT>
static void run_layer(const float* X, const float* W, const float* a_s,
                      const float* a_d, const float* b,
                      const int* offs, const int* csr_src,
                      float* H, float* asrc, float* adst, float* out,
                      hipStream_t stream)
{
    constexpr int COLG = DOUT / 4;
    constexpr int BM = (256 / COLG) * 4;
    const int gemm_grid = (N_NODES + BM - 1) / BM;
    gemm_alpha_kernel<DIN, DOUT><<<gemm_grid, 256, 0, stream>>>(
        X, W, a_s, a_d, H, asrc, adst);

    constexpr int gpb = 256 / DOUT;
    const int agg_grid = (N_NODES + gpb - 1) / gpb;
    node_agg_kernel<DOUT, ACT><<<agg_grid, 256, 0, stream>>>(
        offs, csr_src, asrc, adst, H, b, out);
}

extern "C" void kernel_launch(void* const* d_in, const int* in_sizes, int n_in,
                              void* d_out, int out_size, void* d_ws, size_t ws_size,
                              hipStream_t stream)
{
    const float* x  = (const float*)d_in[0];
    const int*   ei = (const int*)d_in[1];
    const float* W0 = (const float*)d_in[2];
    const float* as0= (const float*)d_in[3];
    const float* ad0= (const float*)d_in[4];
    const float* b0 = (const float*)d_in[5];
    const float* W1 = (const float*)d_in[6];
    const float* as1= (const float*)d_in[7];
    const float* ad1= (const float*)d_in[8];
    const float* b1 = (const float*)d_in[9];
    const float* W2 = (const float*)d_in[10];
    const float* as2= (const float*)d_in[11];
    const float* ad2= (const float*)d_in[12];
    const float* b2 = (const float*)d_in[13];
    float* out = (float*)d_out;

    char* wsb = (char*)d_ws;
    int*  deg     = (int*)wsb;                      wsb += sizeof(int) * N_NODES;
    int*  offs    = (int*)wsb;                      wsb += sizeof(int) * (N_NODES + 1);
    int*  woff    = (int*)wsb;                      wsb += sizeof(int) * N_NODES;
    int*  bsum    = (int*)wsb;                      wsb += sizeof(int) * SCAN_NB;
    int*  csr_src = (int*)wsb;                      wsb += sizeof(int) * ETOT;
    float* buf_h  = (float*)wsb;                    wsb += sizeof(float) * N_NODES * 64;
    float* buf_act= (float*)wsb;                    wsb += sizeof(float) * N_NODES * 64;
    float* asrc   = (float*)wsb;                    wsb += sizeof(float) * N_NODES;
    float* adst   = (float*)wsb;                    wsb += sizeof(float) * N_NODES;

    const int ngrid = (N_NODES + 255) / 256;
    const int egrid = (ETOT + 255) / 256;
    zero_deg_kernel<<<ngrid, 256, 0, stream>>>(deg);
    deg_kernel<<<egrid, 256, 0, stream>>>(ei, deg);
    scan_part_kernel<<<SCAN_NB, 256, 0, stream>>>(deg, bsum);
    scan_top_kernel<<<1, 64, 0, stream>>>(bsum);
    scan_out_kernel<<<SCAN_NB, 256, 0, stream>>>(deg, bsum, offs, woff);
    scatter_kernel<<<egrid, 256, 0, stream>>>(ei, woff, csr_src);

    run_layer<128, 64, 0>(x, W0, as0, ad0, b0, offs, csr_src,
                          buf_h, asrc, adst, buf_act, stream);
    run_layer<64, 64, 0>(buf_act, W1, as1, ad1, b1, offs, csr_src,
                         buf_h, asrc, adst, buf_act, stream);
    run_layer<64, 32, 1>(buf_act, W2, as2, ad2, b2, offs, csr_src,
                         buf_h, asrc, adst, out, stream);
}

// Round 5
// 268.994 us; speedup vs baseline: 3.1973x; 1.0148x over previous
//
#include <hip/hip_runtime.h>
#include <math.h>

#define N_NODES 50000
#define E_EDGES 800000
#define ETOT    (E_EDGES + N_NODES)
#define SCAN_CHUNK 1024
#define SCAN_NB ((N_NODES + SCAN_CHUNK - 1) / SCAN_CHUNK)   // 49

// bucketed scatter params
#define BUCK_SHIFT 9
#define NBUCK ((N_NODES + (1 << BUCK_SHIFT) - 1) >> BUCK_SHIFT)   // 98
#define BS_EPT 16
#define BS_THREADS 256
#define BS_EPB (BS_THREADS * BS_EPT)                              // 4096
#define BS_NBLK ((ETOT + BS_EPB - 1) / BS_EPB)

// ---------------------------------------------------------------------------
// Register-tiled GEMM + alpha epilogue (unchanged from round 4).
// ---------------------------------------------------------------------------
template<int DIN, int DOUT>
__global__ __launch_bounds__(256)
void gemm_alpha_kernel(const float* __restrict__ X, const float* __restrict__ W,
                       const float* __restrict__ a_s, const float* __restrict__ a_d,
                       float* __restrict__ H, float* __restrict__ asrc,
                       float* __restrict__ adst)
{
    constexpr int COLG = DOUT / 4;
    constexpr int ROWG = 256 / COLG;
    constexpr int BM   = ROWG * 4;
    constexpr int K4   = DIN / 4;

    __shared__ float Xl[BM * DIN];
    __shared__ float Wl[DIN * DOUT];

    const int tid = threadIdx.x;
    const int row0b = blockIdx.x * BM;

    constexpr int WV = DIN * DOUT / 4;
    for (int i = tid; i < WV; i += 256)
        ((float4*)Wl)[i] = ((const float4*)W)[i];

    constexpr int XV = BM * K4;
    for (int i = tid; i < XV; i += 256) {
        int r  = i / K4;
        int j  = i % K4;
        int gr = row0b + r;
        float4 v = make_float4(0.f, 0.f, 0.f, 0.f);
        if (gr < N_NODES) v = ((const float4*)X)[gr * K4 + j];
        *(float4*)&Xl[r * DIN + ((j ^ ((r >> 2) & 7)) << 2)] = v;
    }
    __syncthreads();

    const int tx = tid % COLG;
    const int ty = tid / COLG;
    const int r0 = ty * 4;
    const int c0 = tx * 4;
    const int swz = ty & 7;

    float acc[4][4] = {};
    for (int kk = 0; kk < DIN; kk += 4) {
        float a[4][4], w[4][4];
        const int jk = ((kk >> 2) ^ swz) << 2;
#pragma unroll
        for (int i = 0; i < 4; ++i)
            *(float4*)a[i] = *(const float4*)&Xl[(r0 + i) * DIN + jk];
#pragma unroll
        for (int j = 0; j < 4; ++j)
            *(float4*)w[j] = *(const float4*)&Wl[(kk + j) * DOUT + c0];
#pragma unroll
        for (int i = 0; i < 4; ++i)
#pragma unroll
            for (int j = 0; j < 4; ++j)
                acc[i][j] = fmaf(a[i][0], w[0][j],
                            fmaf(a[i][1], w[1][j],
                            fmaf(a[i][2], w[2][j],
                            fmaf(a[i][3], w[3][j], acc[i][j]))));
    }

    float as4[4], ad4[4];
    *(float4*)as4 = *(const float4*)&a_s[c0];
    *(float4*)ad4 = *(const float4*)&a_d[c0];

#pragma unroll
    for (int i = 0; i < 4; ++i) {
        const int gr = row0b + r0 + i;
        float ps = acc[i][0] * as4[0] + acc[i][1] * as4[1] +
                   acc[i][2] * as4[2] + acc[i][3] * as4[3];
        float pd = acc[i][0] * ad4[0] + acc[i][1] * ad4[1] +
                   acc[i][2] * ad4[2] + acc[i][3] * ad4[3];
#pragma unroll
        for (int off = COLG / 2; off >= 1; off >>= 1) {
            ps += __shfl_xor(ps, off, 64);
            pd += __shfl_xor(pd, off, 64);
        }
        if (gr < N_NODES) {
            *(float4*)&H[gr * DOUT + c0] = *(float4*)acc[i];
            if (tx == 0) { asrc[gr] = ps; adst[gr] = pd; }
        }
    }
}

// ---------------------------------------------------------------------------
// CSR build
// ---------------------------------------------------------------------------
__global__ __launch_bounds__(256)
void zero_deg_kernel(int* __restrict__ deg)
{
    int i = blockIdx.x * blockDim.x + threadIdx.x;
    if (i < N_NODES) deg[i] = 0;
}

__global__ __launch_bounds__(256)
void deg_kernel(const int* __restrict__ ei, int* __restrict__ deg)
{
    int eid = blockIdx.x * blockDim.x + threadIdx.x;
    if (eid >= ETOT) return;
    int dst = (eid < E_EDGES) ? ei[E_EDGES + eid] : (eid - E_EDGES);
    atomicAdd(deg + dst, 1);
}

__global__ __launch_bounds__(256)
void scan_part_kernel(const int* __restrict__ deg, int* __restrict__ bsum)
{
    __shared__ int lds[256];
    const int base = blockIdx.x * SCAN_CHUNK;
    int sum = 0;
    for (int i = threadIdx.x; i < SCAN_CHUNK; i += 256) {
        int idx = base + i;
        sum += (idx < N_NODES) ? deg[idx] : 0;
    }
    lds[threadIdx.x] = sum;
    __syncthreads();
    for (int off = 128; off >= 1; off >>= 1) {
        if (threadIdx.x < off) lds[threadIdx.x] += lds[threadIdx.x + off];
        __syncthreads();
    }
    if (threadIdx.x == 0) bsum[blockIdx.x] = lds[0];
}

__global__ __launch_bounds__(64)
void scan_top_kernel(int* __restrict__ bsum)
{
    const int t = threadIdx.x;
    int v = (t < SCAN_NB) ? bsum[t] : 0;
    for (int off = 1; off < 64; off <<= 1) {
        int u = __shfl_up(v, off, 64);
        if (t >= off) v += u;
    }
    int ex = __shfl_up(v, 1, 64);
    if (t == 0) ex = 0;
    if (t < SCAN_NB) bsum[t] = ex;
}

__global__ __launch_bounds__(256)
void scan_out_kernel(const int* __restrict__ deg, const int* __restrict__ bsum,
                     int* __restrict__ offs, int* __restrict__ woff)
{
    __shared__ int lds[256];
    const int t = threadIdx.x;
    const int idx0 = blockIdx.x * SCAN_CHUNK + t * 4;
    int v[4];
    int tsum = 0;
#pragma unroll
    for (int i = 0; i < 4; ++i) {
        int idx = idx0 + i;
        v[i] = (idx < N_NODES) ? deg[idx] : 0;
        tsum += v[i];
    }
    lds[t] = tsum;
    __syncthreads();
    for (int off = 1; off < 256; off <<= 1) {
        int u = (t >= off) ? lds[t - off] : 0;
        __syncthreads();
        lds[t] += u;
        __syncthreads();
    }
    int run = bsum[blockIdx.x] + ((t > 0) ? lds[t - 1] : 0);
#pragma unroll
    for (int i = 0; i < 4; ++i) {
        int idx = idx0 + i;
        if (idx < N_NODES) { offs[idx] = run; woff[idx] = run; run += v[i]; }
    }
    if (blockIdx.x == 0 && t == 0) offs[N_NODES] = ETOT;
}

// cursor[bk] = offs[bk << BUCK_SHIFT]  (bucket base in csr == bucket base in tmp)
__global__ __launch_bounds__(128)
void init_cursor_kernel(const int* __restrict__ offs, int* __restrict__ cur)
{
    int i = blockIdx.x * blockDim.x + threadIdx.x;
    if (i < NBUCK) cur[i] = offs[i << BUCK_SHIFT];
}

// Phase A: bin edges into dst-buckets; per-(block,bucket) contiguous runs in tmp.
__global__ __launch_bounds__(BS_THREADS)
void binscatter_kernel(const int* __restrict__ ei, int* __restrict__ cur,
                       unsigned int* __restrict__ tmp)
{
    __shared__ int lcnt[NBUCK];
    __shared__ int lbase[NBUCK];
    const int t = threadIdx.x;
    for (int i = t; i < NBUCK; i += BS_THREADS) lcnt[i] = 0;
    __syncthreads();

    const int e0 = blockIdx.x * BS_EPB;
    unsigned int pk[BS_EPT];
    int rk[BS_EPT];
    int bk[BS_EPT];
#pragma unroll
    for (int k = 0; k < BS_EPT; ++k) {
        const int eid = e0 + k * BS_THREADS + t;
        bk[k] = -1;
        if (eid < ETOT) {
            int src, dst;
            if (eid < E_EDGES) { src = ei[eid]; dst = ei[E_EDGES + eid]; }
            else               { src = dst = eid - E_EDGES; }
            bk[k] = dst >> BUCK_SHIFT;
            pk[k] = ((unsigned int)dst << 16) | (unsigned int)src;
            rk[k] = atomicAdd(&lcnt[bk[k]], 1);
        }
    }
    __syncthreads();
    for (int i = t; i < NBUCK; i += BS_THREADS)
        if (lcnt[i] > 0) lbase[i] = atomicAdd(&cur[i], lcnt[i]);
    __syncthreads();
#pragma unroll
    for (int k = 0; k < BS_EPT; ++k)
        if (bk[k] >= 0) tmp[lbase[bk[k]] + rk[k]] = pk[k];
}

// Phase B: tmp is bucket-clustered -> final scatter stays in hot L2 windows.
__global__ __launch_bounds__(256)
void final_scatter_kernel(const unsigned int* __restrict__ tmp,
                          int* __restrict__ woff, int* __restrict__ csr_src)
{
    int i = blockIdx.x * blockDim.x + threadIdx.x;
    if (i >= ETOT) return;
    unsigned int v = tmp[i];
    int dst = (int)(v >> 16);
    int src = (int)(v & 0xffffu);
    int pos = atomicAdd(woff + dst, 1);
    csr_src[pos] = src;
}

// ---------------------------------------------------------------------------
// node_agg v2: wave = FL feature-lanes (float4) x SLOTS edge-slots.
// 4 (or 8) H-rows in flight per iteration, no per-edge broadcast loop.
// ---------------------------------------------------------------------------
template<int DOUT, int ACT>
__global__ __launch_bounds__(256)
void node_agg_kernel(const int* __restrict__ offs, const int* __restrict__ csr_src,
                     const float* __restrict__ asrc, const float* __restrict__ adst,
                     const float* __restrict__ H, const float* __restrict__ b,
                     float* __restrict__ out)
{
    constexpr int FL    = DOUT / 4;    // 16 (dout=64) or 8 (dout=32)
    constexpr int SLOTS = 64 / FL;     // 4 or 8
    const int wv   = threadIdx.x >> 6;
    const int lane = threadIdx.x & 63;
    const int fl   = lane % FL;
    const int slot = lane / FL;
    const int node = blockIdx.x * 4 + wv;
    if (node >= N_NODES) return;

    const int beg = offs[node];
    const int end = offs[node + 1];
    const float adn = adst[node];

    float m = -INFINITY, s = 0.f;
    float4 acc = make_float4(0.f, 0.f, 0.f, 0.f);

    for (int cb = beg; cb < end; cb += SLOTS) {
        const int eid = cb + slot;
        const bool valid = (eid < end);
        int src = 0;
        float e = -INFINITY;
        if (valid) {
            src = csr_src[eid];
            float v = asrc[src] + adn;
            e = (v > 0.f) ? v : 0.2f * v;
        }
        float cm = e;
#pragma unroll
        for (int off = FL; off < 64; off <<= 1)
            cm = fmaxf(cm, __shfl_xor(cm, off, 64));
        const float nm = fmaxf(m, cm);
        const float sc = __expf(m - nm);
        const float p  = valid ? __expf(e - nm) : 0.f;
        float ps = p;
#pragma unroll
        for (int off = FL; off < 64; off <<= 1)
            ps += __shfl_xor(ps, off, 64);
        s = s * sc + ps;
        m = nm;

        float4 h = make_float4(0.f, 0.f, 0.f, 0.f);
        if (valid) h = *(const float4*)&H[src * DOUT + fl * 4];
        acc.x = fmaf(p, h.x, acc.x * sc);
        acc.y = fmaf(p, h.y, acc.y * sc);
        acc.z = fmaf(p, h.z, acc.z * sc);
        acc.w = fmaf(p, h.w, acc.w * sc);
    }

    // reduce partial acc across slots
#pragma unroll
    for (int off = FL; off < 64; off <<= 1) {
        acc.x += __shfl_xor(acc.x, off, 64);
        acc.y += __shfl_xor(acc.y, off, 64);
        acc.z += __shfl_xor(acc.z, off, 64);
        acc.w += __shfl_xor(acc.w, off, 64);
    }

    if (slot == 0) {
        const float4 bb = *(const float4*)&b[fl * 4];
        float4 v;
        v.x = acc.x / s + bb.x;
        v.y = acc.y / s + bb.y;
        v.z = acc.z / s + bb.z;
        v.w = acc.w / s + bb.w;
        if (ACT == 0) {
            v.x = fmaxf(v.x, 0.f); v.y = fmaxf(v.y, 0.f);
            v.z = fmaxf(v.z, 0.f); v.w = fmaxf(v.w, 0.f);
        } else {
            v.x = tanhf(v.x); v.y = tanhf(v.y);
            v.z = tanhf(v.z); v.w = tanhf(v.w);
        }
        *(float4*)&out[node * DOUT + fl * 4] = v;
    }
}

// ---------------------------------------------------------------------------

template<int DIN, int DOUT, int ACT>
static void run_layer(const float* X, const float* W, const float* a_s,
                      const float* a_d, const float* b,
                      const int* offs, const int* csr_src,
                      float* H, float* asrc, float* adst, float* out,
                      hipStream_t stream)
{
    constexpr int COLG = DOUT / 4;
    constexpr int BM = (256 / COLG) * 4;
    const int gemm_grid = (N_NODES + BM - 1) / BM;
    gemm_alpha_kernel<DIN, DOUT><<<gemm_grid, 256, 0, stream>>>(
        X, W, a_s, a_d, H, asrc, adst);

    const int agg_grid = (N_NODES + 3) / 4;
    node_agg_kernel<DOUT, ACT><<<agg_grid, 256, 0, stream>>>(
        offs, csr_src, asrc, adst, H, b, out);
}

extern "C" void kernel_launch(void* const* d_in, const int* in_sizes, int n_in,
                              void* d_out, int out_size, void* d_ws, size_t ws_size,
                              hipStream_t stream)
{
    const float* x  = (const float*)d_in[0];
    const int*   ei = (const int*)d_in[1];
    const float* W0 = (const float*)d_in[2];
    const float* as0= (const float*)d_in[3];
    const float* ad0= (const float*)d_in[4];
    const float* b0 = (const float*)d_in[5];
    const float* W1 = (const float*)d_in[6];
    const float* as1= (const float*)d_in[7];
    const float* ad1= (const float*)d_in[8];
    const float* b1 = (const float*)d_in[9];
    const float* W2 = (const float*)d_in[10];
    const float* as2= (const float*)d_in[11];
    const float* ad2= (const float*)d_in[12];
    const float* b2 = (const float*)d_in[13];
    float* out = (float*)d_out;

    // workspace layout — 256B-aligned chunks, floats first (16B alignment for float4)
    char* wsb = (char*)d_ws;
    auto take = [&](size_t bytes) {
        char* p = wsb;
        wsb += (bytes + 255) & ~size_t(255);
        return p;
    };
    float* buf_h   = (float*)take(sizeof(float) * N_NODES * 64);
    float* buf_act = (float*)take(sizeof(float) * N_NODES * 64);
    float* asrc    = (float*)take(sizeof(float) * N_NODES);
    float* adst    = (float*)take(sizeof(float) * N_NODES);
    int*   deg     = (int*)take(sizeof(int) * N_NODES);
    int*   offs    = (int*)take(sizeof(int) * (N_NODES + 1));
    int*   woff    = (int*)take(sizeof(int) * N_NODES);
    int*   bsum    = (int*)take(sizeof(int) * SCAN_NB);
    int*   cur     = (int*)take(sizeof(int) * NBUCK);
    int*   csr_src = (int*)take(sizeof(int) * ETOT);
    // tmp aliases buf_h: dead before first gemm writes H
    unsigned int* tmp = (unsigned int*)buf_h;

    const int ngrid = (N_NODES + 255) / 256;
    const int egrid = (ETOT + 255) / 256;
    zero_deg_kernel<<<ngrid, 256, 0, stream>>>(deg);
    deg_kernel<<<egrid, 256, 0, stream>>>(ei, deg);
    scan_part_kernel<<<SCAN_NB, 256, 0, stream>>>(deg, bsum);
    scan_top_kernel<<<1, 64, 0, stream>>>(bsum);
    scan_out_kernel<<<SCAN_NB, 256, 0, stream>>>(deg, bsum, offs, woff);
    init_cursor_kernel<<<1, 128, 0, stream>>>(offs, cur);
    binscatter_kernel<<<BS_NBLK, BS_THREADS, 0, stream>>>(ei, cur, tmp);
    final_scatter_kernel<<<egrid, 256, 0, stream>>>(tmp, woff, csr_src);

    run_layer<128, 64, 0>(x, W0, as0, ad0, b0, offs, csr_src,
                          buf_h, asrc, adst, buf_act, stream);
    run_layer<64, 64, 0>(buf_act, W1, as1, ad1, b1, offs, csr_src,
                         buf_h, asrc, adst, buf_act, stream);
    run_layer<64, 32, 1>(buf_act, W2, as2, ad2, b2, offs, csr_src,
                         buf_h, asrc, adst, out, stream);
}

// Round 6
// 235.424 us; speedup vs baseline: 3.6532x; 1.1426x over previous
//
#include <hip/hip_runtime.h>
#include <hip/hip_fp16.h>
#include <math.h>

#define N_NODES 50000
#define E_EDGES 800000
#define ETOT    (E_EDGES + N_NODES)
#define SCAN_CHUNK 1024
#define SCAN_NB ((N_NODES + SCAN_CHUNK - 1) / SCAN_CHUNK)   // 49

// bucketed scatter params
#define BUCK_SHIFT 9
#define NBUCK ((N_NODES + (1 << BUCK_SHIFT) - 1) >> BUCK_SHIFT)   // 98
#define BS_EPT 16
#define BS_THREADS 256
#define BS_EPB (BS_THREADS * BS_EPT)                              // 4096
#define BS_NBLK ((ETOT + BS_EPB - 1) / BS_EPB)

// ---------------------------------------------------------------------------
// Register-tiled GEMM + alpha epilogue. H written as fp16 (gather payload).
// ---------------------------------------------------------------------------
template<int DIN, int DOUT>
__global__ __launch_bounds__(256)
void gemm_alpha_kernel(const float* __restrict__ X, const float* __restrict__ W,
                       const float* __restrict__ a_s, const float* __restrict__ a_d,
                       __half* __restrict__ H16, float* __restrict__ asrc,
                       float* __restrict__ adst)
{
    constexpr int COLG = DOUT / 4;
    constexpr int ROWG = 256 / COLG;
    constexpr int BM   = ROWG * 4;
    constexpr int K4   = DIN / 4;

    __shared__ float Xl[BM * DIN];
    __shared__ float Wl[DIN * DOUT];

    const int tid = threadIdx.x;
    const int row0b = blockIdx.x * BM;

    constexpr int WV = DIN * DOUT / 4;
    for (int i = tid; i < WV; i += 256)
        ((float4*)Wl)[i] = ((const float4*)W)[i];

    constexpr int XV = BM * K4;
    for (int i = tid; i < XV; i += 256) {
        int r  = i / K4;
        int j  = i % K4;
        int gr = row0b + r;
        float4 v = make_float4(0.f, 0.f, 0.f, 0.f);
        if (gr < N_NODES) v = ((const float4*)X)[gr * K4 + j];
        *(float4*)&Xl[r * DIN + ((j ^ ((r >> 2) & 7)) << 2)] = v;
    }
    __syncthreads();

    const int tx = tid % COLG;
    const int ty = tid / COLG;
    const int r0 = ty * 4;
    const int c0 = tx * 4;
    const int swz = ty & 7;

    float acc[4][4] = {};
    for (int kk = 0; kk < DIN; kk += 4) {
        float a[4][4], w[4][4];
        const int jk = ((kk >> 2) ^ swz) << 2;
#pragma unroll
        for (int i = 0; i < 4; ++i)
            *(float4*)a[i] = *(const float4*)&Xl[(r0 + i) * DIN + jk];
#pragma unroll
        for (int j = 0; j < 4; ++j)
            *(float4*)w[j] = *(const float4*)&Wl[(kk + j) * DOUT + c0];
#pragma unroll
        for (int i = 0; i < 4; ++i)
#pragma unroll
            for (int j = 0; j < 4; ++j)
                acc[i][j] = fmaf(a[i][0], w[0][j],
                            fmaf(a[i][1], w[1][j],
                            fmaf(a[i][2], w[2][j],
                            fmaf(a[i][3], w[3][j], acc[i][j]))));
    }

    float as4[4], ad4[4];
    *(float4*)as4 = *(const float4*)&a_s[c0];
    *(float4*)ad4 = *(const float4*)&a_d[c0];

#pragma unroll
    for (int i = 0; i < 4; ++i) {
        const int gr = row0b + r0 + i;
        float ps = acc[i][0] * as4[0] + acc[i][1] * as4[1] +
                   acc[i][2] * as4[2] + acc[i][3] * as4[3];
        float pd = acc[i][0] * ad4[0] + acc[i][1] * ad4[1] +
                   acc[i][2] * ad4[2] + acc[i][3] * ad4[3];
#pragma unroll
        for (int off = COLG / 2; off >= 1; off >>= 1) {
            ps += __shfl_xor(ps, off, 64);
            pd += __shfl_xor(pd, off, 64);
        }
        if (gr < N_NODES) {
            __half2 p01 = __floats2half2_rn(acc[i][0], acc[i][1]);
            __half2 p23 = __floats2half2_rn(acc[i][2], acc[i][3]);
            uint2 pk;
            pk.x = *(unsigned int*)&p01;
            pk.y = *(unsigned int*)&p23;
            *(uint2*)&H16[gr * DOUT + c0] = pk;
            if (tx == 0) { asrc[gr] = ps; adst[gr] = pd; }
        }
    }
}

// ---------------------------------------------------------------------------
// CSR build
// ---------------------------------------------------------------------------
__global__ __launch_bounds__(256)
void zero_deg_kernel(int* __restrict__ deg)
{
    int i = blockIdx.x * blockDim.x + threadIdx.x;
    if (i < N_NODES) deg[i] = 0;
}

__global__ __launch_bounds__(256)
void deg_kernel(const int* __restrict__ ei, int* __restrict__ deg)
{
    int eid = blockIdx.x * blockDim.x + threadIdx.x;
    if (eid >= ETOT) return;
    int dst = (eid < E_EDGES) ? ei[E_EDGES + eid] : (eid - E_EDGES);
    atomicAdd(deg + dst, 1);
}

__global__ __launch_bounds__(256)
void scan_part_kernel(const int* __restrict__ deg, int* __restrict__ bsum)
{
    __shared__ int lds[256];
    const int base = blockIdx.x * SCAN_CHUNK;
    int sum = 0;
    for (int i = threadIdx.x; i < SCAN_CHUNK; i += 256) {
        int idx = base + i;
        sum += (idx < N_NODES) ? deg[idx] : 0;
    }
    lds[threadIdx.x] = sum;
    __syncthreads();
    for (int off = 128; off >= 1; off >>= 1) {
        if (threadIdx.x < off) lds[threadIdx.x] += lds[threadIdx.x + off];
        __syncthreads();
    }
    if (threadIdx.x == 0) bsum[blockIdx.x] = lds[0];
}

__global__ __launch_bounds__(64)
void scan_top_kernel(int* __restrict__ bsum)
{
    const int t = threadIdx.x;
    int v = (t < SCAN_NB) ? bsum[t] : 0;
    for (int off = 1; off < 64; off <<= 1) {
        int u = __shfl_up(v, off, 64);
        if (t >= off) v += u;
    }
    int ex = __shfl_up(v, 1, 64);
    if (t == 0) ex = 0;
    if (t < SCAN_NB) bsum[t] = ex;
}

__global__ __launch_bounds__(256)
void scan_out_kernel(const int* __restrict__ deg, const int* __restrict__ bsum,
                     int* __restrict__ offs, int* __restrict__ woff)
{
    __shared__ int lds[256];
    const int t = threadIdx.x;
    const int idx0 = blockIdx.x * SCAN_CHUNK + t * 4;
    int v[4];
    int tsum = 0;
#pragma unroll
    for (int i = 0; i < 4; ++i) {
        int idx = idx0 + i;
        v[i] = (idx < N_NODES) ? deg[idx] : 0;
        tsum += v[i];
    }
    lds[t] = tsum;
    __syncthreads();
    for (int off = 1; off < 256; off <<= 1) {
        int u = (t >= off) ? lds[t - off] : 0;
        __syncthreads();
        lds[t] += u;
        __syncthreads();
    }
    int run = bsum[blockIdx.x] + ((t > 0) ? lds[t - 1] : 0);
#pragma unroll
    for (int i = 0; i < 4; ++i) {
        int idx = idx0 + i;
        if (idx < N_NODES) { offs[idx] = run; woff[idx] = run; run += v[i]; }
    }
    if (blockIdx.x == 0 && t == 0) offs[N_NODES] = ETOT;
}

__global__ __launch_bounds__(128)
void init_cursor_kernel(const int* __restrict__ offs, int* __restrict__ cur)
{
    int i = blockIdx.x * blockDim.x + threadIdx.x;
    if (i < NBUCK) cur[i] = offs[i << BUCK_SHIFT];
}

__global__ __launch_bounds__(BS_THREADS)
void binscatter_kernel(const int* __restrict__ ei, int* __restrict__ cur,
                       unsigned int* __restrict__ tmp)
{
    __shared__ int lcnt[NBUCK];
    __shared__ int lbase[NBUCK];
    const int t = threadIdx.x;
    for (int i = t; i < NBUCK; i += BS_THREADS) lcnt[i] = 0;
    __syncthreads();

    const int e0 = blockIdx.x * BS_EPB;
    unsigned int pk[BS_EPT];
    int rk[BS_EPT];
    int bk[BS_EPT];
#pragma unroll
    for (int k = 0; k < BS_EPT; ++k) {
        const int eid = e0 + k * BS_THREADS + t;
        bk[k] = -1;
        if (eid < ETOT) {
            int src, dst;
            if (eid < E_EDGES) { src = ei[eid]; dst = ei[E_EDGES + eid]; }
            else               { src = dst = eid - E_EDGES; }
            bk[k] = dst >> BUCK_SHIFT;
            pk[k] = ((unsigned int)dst << 16) | (unsigned int)src;
            rk[k] = atomicAdd(&lcnt[bk[k]], 1);
        }
    }
    __syncthreads();
    for (int i = t; i < NBUCK; i += BS_THREADS)
        if (lcnt[i] > 0) lbase[i] = atomicAdd(&cur[i], lcnt[i]);
    __syncthreads();
#pragma unroll
    for (int k = 0; k < BS_EPT; ++k)
        if (bk[k] >= 0) tmp[lbase[bk[k]] + rk[k]] = pk[k];
}

__global__ __launch_bounds__(256)
void final_scatter_kernel(const unsigned int* __restrict__ tmp,
                          int* __restrict__ woff, int* __restrict__ csr_src)
{
    int i = blockIdx.x * blockDim.x + threadIdx.x;
    if (i >= ETOT) return;
    unsigned int v = tmp[i];
    int dst = (int)(v >> 16);
    int src = (int)(v & 0xffffu);
    int pos = atomicAdd(woff + dst, 1);
    csr_src[pos] = src;
}

// ---------------------------------------------------------------------------
// node_agg v3: no online max (exp(e) directly, clamp 80 for safety),
// fp16 H gather, zero cross-lane ops in the inner loop.
// wave = FL feature-lanes (float4) x SLOTS edge-slots; per-slot partial s/acc.
// ---------------------------------------------------------------------------
template<int DOUT, int ACT>
__global__ __launch_bounds__(256)
void node_agg_kernel(const int* __restrict__ offs, const int* __restrict__ csr_src,
                     const float* __restrict__ asrc, const float* __restrict__ adst,
                     const __half* __restrict__ H16, const float* __restrict__ b,
                     float* __restrict__ out)
{
    constexpr int FL    = DOUT / 4;    // 16 (dout=64) or 8 (dout=32)
    constexpr int SLOTS = 64 / FL;     // 4 or 8
    const int wv   = threadIdx.x >> 6;
    const int lane = threadIdx.x & 63;
    const int fl   = lane % FL;
    const int slot = lane / FL;
    const int node = blockIdx.x * 4 + wv;
    if (node >= N_NODES) return;

    const int beg = offs[node];
    const int end = offs[node + 1];
    const float adn = adst[node];

    float s = 0.f;
    float4 acc = make_float4(0.f, 0.f, 0.f, 0.f);

    for (int cb = beg; cb < end; cb += SLOTS) {
        const int eid = cb + slot;
        const bool valid = (eid < end);
        float p = 0.f;
        float2 f01 = make_float2(0.f, 0.f), f23 = make_float2(0.f, 0.f);
        if (valid) {
            const int src = csr_src[eid];
            float v = asrc[src] + adn;
            v = (v > 0.f) ? v : 0.2f * v;
            p = __expf(fminf(v, 80.f));
            const __half2* hp = (const __half2*)(H16 + src * DOUT + fl * 4);
            f01 = __half22float2(hp[0]);
            f23 = __half22float2(hp[1]);
        }
        s += p;
        acc.x = fmaf(p, f01.x, acc.x);
        acc.y = fmaf(p, f01.y, acc.y);
        acc.z = fmaf(p, f23.x, acc.z);
        acc.w = fmaf(p, f23.y, acc.w);
    }

    // reduce partial s/acc across slots
#pragma unroll
    for (int off = FL; off < 64; off <<= 1) {
        s     += __shfl_xor(s, off, 64);
        acc.x += __shfl_xor(acc.x, off, 64);
        acc.y += __shfl_xor(acc.y, off, 64);
        acc.z += __shfl_xor(acc.z, off, 64);
        acc.w += __shfl_xor(acc.w, off, 64);
    }

    if (slot == 0) {
        const float4 bb = *(const float4*)&b[fl * 4];
        const float inv = 1.f / s;
        float4 v;
        v.x = acc.x * inv + bb.x;
        v.y = acc.y * inv + bb.y;
        v.z = acc.z * inv + bb.z;
        v.w = acc.w * inv + bb.w;
        if (ACT == 0) {
            v.x = fmaxf(v.x, 0.f); v.y = fmaxf(v.y, 0.f);
            v.z = fmaxf(v.z, 0.f); v.w = fmaxf(v.w, 0.f);
        } else {
            v.x = tanhf(v.x); v.y = tanhf(v.y);
            v.z = tanhf(v.z); v.w = tanhf(v.w);
        }
        *(float4*)&out[node * DOUT + fl * 4] = v;
    }
}

// ---------------------------------------------------------------------------

template<int DIN, int DOUT, int ACT>
static void run_layer(const float* X, const float* W, const float* a_s,
                      const float* a_d, const float* b,
                      const int* offs, const int* csr_src,
                      __half* H16, float* asrc, float* adst, float* out,
                      hipStream_t stream)
{
    constexpr int COLG = DOUT / 4;
    constexpr int BM = (256 / COLG) * 4;
    const int gemm_grid = (N_NODES + BM - 1) / BM;
    gemm_alpha_kernel<DIN, DOUT><<<gemm_grid, 256, 0, stream>>>(
        X, W, a_s, a_d, H16, asrc, adst);

    const int agg_grid = (N_NODES + 3) / 4;
    node_agg_kernel<DOUT, ACT><<<agg_grid, 256, 0, stream>>>(
        offs, csr_src, asrc, adst, H16, b, out);
}

extern "C" void kernel_launch(void* const* d_in, const int* in_sizes, int n_in,
                              void* d_out, int out_size, void* d_ws, size_t ws_size,
                              hipStream_t stream)
{
    const float* x  = (const float*)d_in[0];
    const int*   ei = (const int*)d_in[1];
    const float* W0 = (const float*)d_in[2];
    const float* as0= (const float*)d_in[3];
    const float* ad0= (const float*)d_in[4];
    const float* b0 = (const float*)d_in[5];
    const float* W1 = (const float*)d_in[6];
    const float* as1= (const float*)d_in[7];
    const float* ad1= (const float*)d_in[8];
    const float* b1 = (const float*)d_in[9];
    const float* W2 = (const float*)d_in[10];
    const float* as2= (const float*)d_in[11];
    const float* ad2= (const float*)d_in[12];
    const float* b2 = (const float*)d_in[13];
    float* out = (float*)d_out;

    char* wsb = (char*)d_ws;
    auto take = [&](size_t bytes) {
        char* p = wsb;
        wsb += (bytes + 255) & ~size_t(255);
        return p;
    };
    __half* h16    = (__half*)take(sizeof(__half) * N_NODES * 64);
    float* buf_act = (float*)take(sizeof(float) * N_NODES * 64);
    float* asrc    = (float*)take(sizeof(float) * N_NODES);
    float* adst    = (float*)take(sizeof(float) * N_NODES);
    int*   deg     = (int*)take(sizeof(int) * N_NODES);
    int*   offs    = (int*)take(sizeof(int) * (N_NODES + 1));
    int*   woff    = (int*)take(sizeof(int) * N_NODES);
    int*   bsum    = (int*)take(sizeof(int) * SCAN_NB);
    int*   cur     = (int*)take(sizeof(int) * NBUCK);
    int*   csr_src = (int*)take(sizeof(int) * ETOT);
    // tmp aliases h16: dead before the first gemm writes H16
    unsigned int* tmp = (unsigned int*)h16;

    const int ngrid = (N_NODES + 255) / 256;
    const int egrid = (ETOT + 255) / 256;
    zero_deg_kernel<<<ngrid, 256, 0, stream>>>(deg);
    deg_kernel<<<egrid, 256, 0, stream>>>(ei, deg);
    scan_part_kernel<<<SCAN_NB, 256, 0, stream>>>(deg, bsum);
    scan_top_kernel<<<1, 64, 0, stream>>>(bsum);
    scan_out_kernel<<<SCAN_NB, 256, 0, stream>>>(deg, bsum, offs, woff);
    init_cursor_kernel<<<1, 128, 0, stream>>>(offs, cur);
    binscatter_kernel<<<BS_NBLK, BS_THREADS, 0, stream>>>(ei, cur, tmp);
    final_scatter_kernel<<<egrid, 256, 0, stream>>>(tmp, woff, csr_src);

    run_layer<128, 64, 0>(x, W0, as0, ad0, b0, offs, csr_src,
                          h16, asrc, adst, buf_act, stream);
    run_layer<64, 64, 0>(buf_act, W1, as1, ad1, b1, offs, csr_src,
                         h16, asrc, adst, buf_act, stream);
    run_layer<64, 32, 1>(buf_act, W2, as2, ad2, b2, offs, csr_src,
                         h16, asrc, adst, out, stream);
}